// Round 1
// baseline (285.764 us; speedup 1.0000x reference)
//
#include <hip/hip_runtime.h>
#include <math.h>

#define B_ 2
#define C_ 128
#define H_ 56
#define W_ 56
#define N_ (H_*W_)      // 3136
#define HEADS_ 4
#define DH_ 32
#define MW_ 28          // W/2
#define TPX 32          // pixels per tile for the GEMM-ish kernels

// ---------------------------------------------------------------------------
// Kernel A: asym gate pre-values aval[b][h][j], j in [0,28)
//   cat = [left, flip(right)] channels (256), a1 = gelu(Wa1 cat + ba1),
//   aval = sigmoid(Wa2 a1 + ba2)
// one block (128 threads) per (b,h,j); thread t computes output channel t.
// ---------------------------------------------------------------------------
__global__ __launch_bounds__(128)
void asym_kernel(const float* __restrict__ x,
                 const float* __restrict__ Wa1, const float* __restrict__ ba1,
                 const float* __restrict__ Wa2, const float* __restrict__ ba2,
                 float* __restrict__ aval) {
    int blk = blockIdx.x;            // 0 .. B*H*MW-1
    int j = blk % MW_;
    int h = (blk / MW_) % H_;
    int b = blk / (MW_ * H_);
    int tid = threadIdx.x;           // 128 threads

    __shared__ float catv[2 * C_];
    __shared__ float red[128];

    const float* xb = x + (size_t)b * C_ * N_;
    // left half channel tid, and flipped right half
    catv[tid]       = xb[(size_t)tid * N_ + h * W_ + j];
    catv[128 + tid] = xb[(size_t)tid * N_ + h * W_ + (W_ - 1 - j)];
    __syncthreads();

    const float* wrow = Wa1 + (size_t)tid * (2 * C_);
    float acc = ba1[tid];
    #pragma unroll 8
    for (int c = 0; c < 2 * C_; ++c) acc += wrow[c] * catv[c];

    // exact gelu: 0.5*x*(1+erf(x/sqrt(2)))
    float g = 0.5f * acc * (1.0f + erff(acc * 0.7071067811865475f));
    red[tid] = g * Wa2[tid];
    __syncthreads();

    for (int s = 64; s > 0; s >>= 1) {
        if (tid < s) red[tid] += red[tid + s];
        __syncthreads();
    }
    if (tid == 0) {
        float a2 = red[0] + ba2[0];
        aval[(size_t)b * H_ * MW_ + h * MW_ + j] = 1.0f / (1.0f + expf(-a2));
    }
}

// ---------------------------------------------------------------------------
// Kernel B: q,k,v projections. x is (b,c,n); outputs stored pixel-major
// (b,n,c) so attention reads contiguous 32-float head vectors.
// Block: 256 threads, handles TPX pixels x 384 outputs.
// ---------------------------------------------------------------------------
__global__ __launch_bounds__(256)
void qkv_kernel(const float* __restrict__ x,
                const float* __restrict__ Wq, const float* __restrict__ Wk,
                const float* __restrict__ Wv,
                float* __restrict__ q, float* __restrict__ k, float* __restrict__ v) {
    int b  = blockIdx.y;
    int n0 = blockIdx.x * TPX;
    int tid = threadIdx.x;

    __shared__ float xs[C_][TPX];    // 16 KB; compute-loop reads are bank-clean
    const float* xb = x + (size_t)b * C_ * N_;
    for (int i = tid; i < C_ * TPX; i += 256) {
        int c = i / TPX, p = i % TPX;
        xs[c][p] = xb[(size_t)c * N_ + n0 + p];
    }
    __syncthreads();

    for (int i = tid; i < 3 * C_ * TPX; i += 256) {
        int p = i % TPX;
        int o = (i / TPX) % C_;
        int m = i / (TPX * C_);
        const float* W  = (m == 0 ? Wq : (m == 1 ? Wk : Wv));
        const float* wr = W + (size_t)o * C_;
        float acc = 0.f;
        #pragma unroll 8
        for (int c = 0; c < C_; ++c) acc += wr[c] * xs[c][p];
        float* dst = (m == 0 ? q : (m == 1 ? k : v));
        dst[((size_t)b * N_ + n0 + p) * C_ + o] = acc;
    }
}

// ---------------------------------------------------------------------------
// Kernel C: 3x3 neighborhood attention + asym gating.
// One thread per (b, head, n). q/k/v are (b,n,c) pixel-major.
// Writes attention output (b,n,c), pre-scaled by (1 + 0.5*asym).
// ---------------------------------------------------------------------------
__global__ __launch_bounds__(256)
void attn_kernel(const float* __restrict__ q, const float* __restrict__ k,
                 const float* __restrict__ v, const float* __restrict__ aval,
                 float* __restrict__ ao) {
    int gid = blockIdx.x * blockDim.x + threadIdx.x;
    if (gid >= B_ * HEADS_ * N_) return;
    int n    = gid % N_;
    int head = (gid / N_) % HEADS_;
    int b    = gid / (N_ * HEADS_);
    int i = n / W_, j = n % W_;
    const float scale = 0.17677669529663687f;   // 1/sqrt(32)

    const float* qv = q + ((size_t)b * N_ + n) * C_ + head * DH_;
    float qr[DH_];
    #pragma unroll
    for (int d = 0; d < DH_; ++d) qr[d] = qv[d];

    float dots[9];
    int   nn[9];
    int   cnt = 0;
    float mx = -1e30f;
    for (int di = -1; di <= 1; ++di) {
        int ii = i + di;
        if (ii < 0 || ii >= H_) continue;
        for (int dj = -1; dj <= 1; ++dj) {
            int jj = j + dj;
            if (jj < 0 || jj >= W_) continue;
            int m = ii * W_ + jj;
            const float* kv = k + ((size_t)b * N_ + m) * C_ + head * DH_;
            float d0 = 0.f;
            #pragma unroll
            for (int d = 0; d < DH_; ++d) d0 += qr[d] * kv[d];
            d0 *= scale;
            dots[cnt] = d0; nn[cnt] = m; ++cnt;
            mx = fmaxf(mx, d0);
        }
    }
    float sum = 0.f;
    for (int t = 0; t < cnt; ++t) { dots[t] = expf(dots[t] - mx); sum += dots[t]; }
    float inv = 1.0f / sum;

    float acc[DH_];
    #pragma unroll
    for (int d = 0; d < DH_; ++d) acc[d] = 0.f;
    for (int t = 0; t < cnt; ++t) {
        const float* vv = v + ((size_t)b * N_ + nn[t]) * C_ + head * DH_;
        float w = dots[t] * inv;
        #pragma unroll
        for (int d = 0; d < DH_; ++d) acc[d] += w * vv[d];
    }

    // asym: linear resize 28 -> 56 along width (half-pixel centers, clamped
    // edges match jax.image.resize's renormalization), identity along height.
    float f = 0.5f * (float)j - 0.25f;
    f = fminf(fmaxf(f, 0.0f), 27.0f);
    int i0 = (int)f; if (i0 > 26) i0 = 26;
    float frac = f - (float)i0;
    const float* av = aval + (size_t)b * H_ * MW_ + i * MW_;
    float a = av[i0] * (1.0f - frac) + av[i0 + 1] * frac;
    float s = 1.0f + 0.5f * a;

    float* dst = ao + ((size_t)b * N_ + n) * C_ + head * DH_;
    #pragma unroll
    for (int d = 0; d < DH_; ++d) dst[d] = acc[d] * s;
}

// ---------------------------------------------------------------------------
// Kernel D: output projection. ao is (b,n,c); out is (b,o,h,w) channel-major.
// ---------------------------------------------------------------------------
__global__ __launch_bounds__(256)
void oproj_kernel(const float* __restrict__ ao, const float* __restrict__ Wo,
                  const float* __restrict__ bo, float* __restrict__ out) {
    int b  = blockIdx.y;
    int n0 = blockIdx.x * TPX;
    int tid = threadIdx.x;

    __shared__ float ts[TPX][C_ + 1];   // +1 pad: compute reads stride 129 -> bank-clean
    const float* src = ao + ((size_t)b * N_ + n0) * C_;
    for (int i = tid; i < TPX * C_; i += 256) {
        int p = i / C_, c = i % C_;
        ts[p][c] = src[(size_t)p * C_ + c];
    }
    __syncthreads();

    for (int i = tid; i < C_ * TPX; i += 256) {
        int p = i % TPX;
        int o = i / TPX;
        const float* wr = Wo + (size_t)o * C_;
        float acc = bo[o];
        #pragma unroll 8
        for (int c = 0; c < C_; ++c) acc += wr[c] * ts[p][c];
        out[(size_t)b * C_ * N_ + (size_t)o * N_ + n0 + p] = acc;
    }
}

// ---------------------------------------------------------------------------
extern "C" void kernel_launch(void* const* d_in, const int* in_sizes, int n_in,
                              void* d_out, int out_size, void* d_ws, size_t ws_size,
                              hipStream_t stream) {
    const float* x   = (const float*)d_in[0];
    const float* Wq  = (const float*)d_in[1];
    const float* Wk  = (const float*)d_in[2];
    const float* Wv  = (const float*)d_in[3];
    const float* Wo  = (const float*)d_in[4];
    const float* bo  = (const float*)d_in[5];
    const float* Wa1 = (const float*)d_in[6];
    const float* ba1 = (const float*)d_in[7];
    const float* Wa2 = (const float*)d_in[8];
    const float* ba2 = (const float*)d_in[9];
    float* out = (float*)d_out;

    // workspace layout (floats)
    const size_t PXC = (size_t)B_ * N_ * C_;   // 802816
    float* q    = (float*)d_ws;
    float* k    = q + PXC;
    float* v    = k + PXC;
    float* ao   = v + PXC;
    float* aval = ao + PXC;                    // B*H*MW = 3136 floats

    asym_kernel<<<B_ * H_ * MW_, 128, 0, stream>>>(x, Wa1, ba1, Wa2, ba2, aval);
    qkv_kernel<<<dim3(N_ / TPX, B_), 256, 0, stream>>>(x, Wq, Wk, Wv, q, k, v);
    attn_kernel<<<(B_ * HEADS_ * N_ + 255) / 256, 256, 0, stream>>>(q, k, v, aval, ao);
    oproj_kernel<<<dim3(N_ / TPX, B_), 256, 0, stream>>>(ao, Wo, bo, out);
}

// Round 2
// 124.946 us; speedup vs baseline: 2.2871x; 2.2871x over previous
//
#include <hip/hip_runtime.h>
#include <math.h>

#define B_ 2
#define C_ 128
#define H_ 56
#define W_ 56
#define N_ (H_*W_)      // 3136
#define HEADS_ 4
#define DH_ 32
#define MW_ 28          // W/2

// ---------------------------------------------------------------------------
// Kernel A: asym gate pre-values aval[b][h][j], j in [0,28)
// Block: 128 threads handles 4 consecutive j positions for one (b,h).
// Thread t computes hidden channel t for all 4 positions (Wa1 row read once).
// ---------------------------------------------------------------------------
__global__ __launch_bounds__(128)
void asym_kernel(const float* __restrict__ x,
                 const float* __restrict__ Wa1, const float* __restrict__ ba1,
                 const float* __restrict__ Wa2, const float* __restrict__ ba2,
                 float* __restrict__ aval) {
    const int jg = blockIdx.x;       // 0..6  (4 j's each)
    const int h  = blockIdx.y;
    const int b  = blockIdx.z;
    const int t  = threadIdx.x;      // 0..127

    __shared__ float catS[4][260];   // [pos][cat-channel], pad 260 = 4 mod 32
    __shared__ float wred[2][4];

    const float* xb = x + (size_t)b * C_ * N_;
    const int row = h * W_;
    // stage cat: 4 positions x 256 channels. idx -> pos fastest (16B global segs)
    for (int it = 0; it < 8; ++it) {
        int idx = t + it * 128;          // 0..1023
        int pos = idx & 3;
        int ch  = idx >> 2;              // 0..255
        int j   = jg * 4 + pos;
        int c   = ch & 127;
        int col = (ch < 128) ? j : (W_ - 1 - j);
        catS[pos][ch] = xb[(size_t)c * N_ + row + col];
    }
    __syncthreads();

    float acc[4];
    float bias = ba1[t];
    #pragma unroll
    for (int p = 0; p < 4; ++p) acc[p] = bias;

    const float* wr = Wa1 + (size_t)t * (2 * C_);
    for (int c = 0; c < 2 * C_; c += 4) {
        float4 wv = *(const float4*)(wr + c);
        #pragma unroll
        for (int p = 0; p < 4; ++p) {
            float4 cv = *(const float4*)(&catS[p][c]);
            acc[p] += wv.x * cv.x + wv.y * cv.y + wv.z * cv.z + wv.w * cv.w;
        }
    }
    const float wa2 = Wa2[t];
    float g[4];
    #pragma unroll
    for (int p = 0; p < 4; ++p) {
        float a = acc[p];
        g[p] = 0.5f * a * (1.0f + erff(a * 0.7071067811865475f)) * wa2;
    }
    // reduce over 128 channels: per-wave shuffle, then combine 2 waves via LDS
    #pragma unroll
    for (int off = 32; off > 0; off >>= 1) {
        #pragma unroll
        for (int p = 0; p < 4; ++p) g[p] += __shfl_xor(g[p], off, 64);
    }
    if ((t & 63) == 0) {
        int wv_ = t >> 6;
        #pragma unroll
        for (int p = 0; p < 4; ++p) wred[wv_][p] = g[p];
    }
    __syncthreads();
    if (t < 4) {
        float tot = wred[0][t] + wred[1][t] + ba2[0];
        aval[(size_t)b * H_ * MW_ + h * MW_ + jg * 4 + t] =
            1.0f / (1.0f + expf(-tot));
    }
}

// ---------------------------------------------------------------------------
// Kernel B: q,k,v projections as 64px x 64out register-blocked tiles.
// x channel-major [b][c][n]; outputs pixel-major [b][n][c] (for attn).
// Thread (og=t&15, pg=t>>4) computes 4 px (pg*4+i) x 4 outs (og+16j).
// All hot-loop LDS traffic is ds_read_b128, bank-conflict-free mappings.
// ---------------------------------------------------------------------------
__global__ __launch_bounds__(256)
void qkv_kernel(const float* __restrict__ x,
                const float* __restrict__ Wq, const float* __restrict__ Wk,
                const float* __restrict__ Wv,
                float* __restrict__ q, float* __restrict__ k, float* __restrict__ v) {
    const int n0 = blockIdx.x * 64;          // pixel tile (49)
    const int ot = blockIdx.y;               // 0..5: matrix*2 + out-half
    const int b  = blockIdx.z;
    const int m  = ot >> 1;
    const int o0 = (ot & 1) * 64;
    const float* W = (m == 0 ? Wq : (m == 1 ? Wk : Wv));
    float* dst     = (m == 0 ? q  : (m == 1 ? k  : v ));

    __shared__ float xs[64][68];      // half the channels at a time (17408 B)
    __shared__ float ws[64][132];     // full 64-row x 128-col W tile (33792 B)

    const int t  = threadIdx.x;
    const int og = t & 15;
    const int pg = t >> 4;
    const float* xb = x + (size_t)b * C_ * N_;

    // stage W tile once: 64 rows x 32 float4, coalesced
    for (int it = 0; it < 8; ++it) {
        int idx = t + it * 256;
        int r = idx >> 5, f4 = idx & 31;
        *(float4*)(&ws[r][f4 * 4]) =
            *(const float4*)(W + (size_t)(o0 + r) * C_ + f4 * 4);
    }

    float acc[4][4];
    #pragma unroll
    for (int i = 0; i < 4; ++i)
        #pragma unroll
        for (int j = 0; j < 4; ++j) acc[i][j] = 0.f;

    for (int chb = 0; chb < C_; chb += 64) {
        __syncthreads();   // previous-iter readers done (also covers ws stage)
        // stage xs: 64 channels x 16 float4 of pixels, coalesced
        for (int it = 0; it < 4; ++it) {
            int idx = t + it * 256;          // 0..1023
            int c = idx >> 4, f4 = idx & 15;
            *(float4*)(&xs[c][f4 * 4]) =
                *(const float4*)(xb + (size_t)(chb + c) * N_ + n0 + f4 * 4);
        }
        __syncthreads();

        for (int cl = 0; cl < 64; cl += 4) {
            float4 xv[4], wv[4];
            #pragma unroll
            for (int ci = 0; ci < 4; ++ci)
                xv[ci] = *(const float4*)(&xs[cl + ci][pg * 4]);
            #pragma unroll
            for (int j = 0; j < 4; ++j)
                wv[j] = *(const float4*)(&ws[og + 16 * j][chb + cl]);
            #pragma unroll
            for (int j = 0; j < 4; ++j) {
                const float* wf = (const float*)&wv[j];
                #pragma unroll
                for (int ci = 0; ci < 4; ++ci) {
                    float wsc = wf[ci];
                    acc[0][j] += xv[ci].x * wsc;
                    acc[1][j] += xv[ci].y * wsc;
                    acc[2][j] += xv[ci].z * wsc;
                    acc[3][j] += xv[ci].w * wsc;
                }
            }
        }
    }

    // epilogue: transpose through LDS (reuse xs) for coalesced float4 stores
    __syncthreads();
    float (*ot_)[68] = (float (*)[68])&xs[0][0];    // [px][o_local]
    #pragma unroll
    for (int i = 0; i < 4; ++i)
        #pragma unroll
        for (int j = 0; j < 4; ++j)
            ot_[pg * 4 + i][og + 16 * j] = acc[i][j];
    __syncthreads();
    for (int it = 0; it < 4; ++it) {
        int idx = t + it * 256;              // 64 px x 16 f4
        int p = idx >> 4, f4 = idx & 15;
        *(float4*)(dst + ((size_t)b * N_ + n0 + p) * C_ + o0 + f4 * 4) =
            *(const float4*)(&ot_[p][f4 * 4]);
    }
}

// ---------------------------------------------------------------------------
// Kernel C: 3x3 neighborhood attention + asym gating.
// 4 lanes per (b,head,n): lane slice s=gid&3 owns 8 of the 32 head dims.
// Dots shuffle-reduced across the 4-lane group. Output channel-major [b][c][n]
// pre-scaled by (1 + 0.5*asym) so oproj stages it exactly like x.
// ---------------------------------------------------------------------------
__global__ __launch_bounds__(256)
void attn_kernel(const float* __restrict__ q, const float* __restrict__ k,
                 const float* __restrict__ v, const float* __restrict__ aval,
                 float* __restrict__ ao) {
    const int gid = blockIdx.x * 256 + threadIdx.x;   // B*HEADS*N*4 = 100352
    const int s    = gid & 3;
    const int rest = gid >> 2;
    const int n    = rest % N_;
    const int hb   = rest / N_;          // b*HEADS + head
    const int head = hb & (HEADS_ - 1);
    const int b    = hb >> 2;
    const int i = n / W_, j = n - i * W_;
    const int dbase = head * DH_ + s * 8;

    const float* qp = q + ((size_t)b * N_ + n) * C_ + dbase;
    const float4 q0 = *(const float4*)qp;
    const float4 q1 = *(const float4*)(qp + 4);

    float dts[9];
    int   mm[9];
    #pragma unroll
    for (int tt = 0; tt < 9; ++tt) {
        int di = tt / 3 - 1, dj = tt % 3 - 1;
        int ii = i + di, jj = j + dj;
        bool ok = ((unsigned)ii < (unsigned)H_) && ((unsigned)jj < (unsigned)W_);
        int m = ok ? ii * W_ + jj : n;
        mm[tt] = m;
        const float* kp = k + ((size_t)b * N_ + m) * C_ + dbase;
        float4 k0 = *(const float4*)kp;
        float4 k1 = *(const float4*)(kp + 4);
        float pd = q0.x*k0.x + q0.y*k0.y + q0.z*k0.z + q0.w*k0.w
                 + q1.x*k1.x + q1.y*k1.y + q1.z*k1.z + q1.w*k1.w;
        pd += __shfl_xor(pd, 1, 64);
        pd += __shfl_xor(pd, 2, 64);
        dts[tt] = ok ? pd * 0.17677669529663687f : -1e30f;  // 1/sqrt(32)
    }
    float mx = dts[0];
    #pragma unroll
    for (int tt = 1; tt < 9; ++tt) mx = fmaxf(mx, dts[tt]);
    float sum = 0.f;
    #pragma unroll
    for (int tt = 0; tt < 9; ++tt) { dts[tt] = expf(dts[tt] - mx); sum += dts[tt]; }
    const float inv = 1.0f / sum;

    float4 a0 = {0,0,0,0}, a1 = {0,0,0,0};
    #pragma unroll
    for (int tt = 0; tt < 9; ++tt) {
        const float* vp = v + ((size_t)b * N_ + mm[tt]) * C_ + dbase;
        float4 v0 = *(const float4*)vp;
        float4 v1 = *(const float4*)(vp + 4);
        float wt = dts[tt] * inv;
        a0.x += wt * v0.x; a0.y += wt * v0.y; a0.z += wt * v0.z; a0.w += wt * v0.w;
        a1.x += wt * v1.x; a1.y += wt * v1.y; a1.z += wt * v1.z; a1.w += wt * v1.w;
    }

    // asym: linear 28->56 along width (half-pixel centers, clamped edges)
    float f = 0.5f * (float)j - 0.25f;
    f = fminf(fmaxf(f, 0.0f), 27.0f);
    int i0 = (int)f; if (i0 > 26) i0 = 26;
    float frac = f - (float)i0;
    const float* av = aval + (size_t)b * H_ * MW_ + i * MW_;
    float a = av[i0] * (1.0f - frac) + av[i0 + 1] * frac;
    float sc = 1.0f + 0.5f * a;

    float* op = ao + (size_t)b * C_ * N_ + (size_t)dbase * N_ + n;
    op[0 * N_] = a0.x * sc; op[1 * N_] = a0.y * sc;
    op[2 * N_] = a0.z * sc; op[3 * N_] = a0.w * sc;
    op[4 * N_] = a1.x * sc; op[5 * N_] = a1.y * sc;
    op[6 * N_] = a1.z * sc; op[7 * N_] = a1.w * sc;
}

// ---------------------------------------------------------------------------
// Kernel D: output projection, same tile structure as qkv.
// ao channel-major [b][c][n] -> out channel-major [b][o][h][w] (= d_out).
// ---------------------------------------------------------------------------
__global__ __launch_bounds__(256)
void oproj_kernel(const float* __restrict__ ao, const float* __restrict__ Wo,
                  const float* __restrict__ bo, float* __restrict__ out) {
    const int n0 = blockIdx.x * 64;          // 49
    const int o0 = blockIdx.y * 64;          // 2
    const int b  = blockIdx.z;

    __shared__ float xs[64][68];
    __shared__ float ws[64][132];

    const int t  = threadIdx.x;
    const int og = t & 15;
    const int pg = t >> 4;
    const float* xb = ao + (size_t)b * C_ * N_;

    for (int it = 0; it < 8; ++it) {
        int idx = t + it * 256;
        int r = idx >> 5, f4 = idx & 31;
        *(float4*)(&ws[r][f4 * 4]) =
            *(const float4*)(Wo + (size_t)(o0 + r) * C_ + f4 * 4);
    }

    float acc[4][4];
    #pragma unroll
    for (int j = 0; j < 4; ++j) {
        float bj = bo[o0 + og + 16 * j];
        #pragma unroll
        for (int i = 0; i < 4; ++i) acc[i][j] = bj;
    }

    for (int chb = 0; chb < C_; chb += 64) {
        __syncthreads();
        for (int it = 0; it < 4; ++it) {
            int idx = t + it * 256;
            int c = idx >> 4, f4 = idx & 15;
            *(float4*)(&xs[c][f4 * 4]) =
                *(const float4*)(xb + (size_t)(chb + c) * N_ + n0 + f4 * 4);
        }
        __syncthreads();

        for (int cl = 0; cl < 64; cl += 4) {
            float4 xv[4], wv[4];
            #pragma unroll
            for (int ci = 0; ci < 4; ++ci)
                xv[ci] = *(const float4*)(&xs[cl + ci][pg * 4]);
            #pragma unroll
            for (int j = 0; j < 4; ++j)
                wv[j] = *(const float4*)(&ws[og + 16 * j][chb + cl]);
            #pragma unroll
            for (int j = 0; j < 4; ++j) {
                const float* wf = (const float*)&wv[j];
                #pragma unroll
                for (int ci = 0; ci < 4; ++ci) {
                    float wsc = wf[ci];
                    acc[0][j] += xv[ci].x * wsc;
                    acc[1][j] += xv[ci].y * wsc;
                    acc[2][j] += xv[ci].z * wsc;
                    acc[3][j] += xv[ci].w * wsc;
                }
            }
        }
    }

    // transpose epilogue: [o_local][px] so channel-major stores are float4
    __syncthreads();
    float (*ot2)[68] = (float (*)[68])&xs[0][0];
    #pragma unroll
    for (int i = 0; i < 4; ++i)
        #pragma unroll
        for (int j = 0; j < 4; ++j)
            ot2[og + 16 * j][pg * 4 + i] = acc[i][j];
    __syncthreads();
    for (int it = 0; it < 4; ++it) {
        int idx = t + it * 256;              // 64 o x 16 f4
        int o = idx >> 4, f4 = idx & 15;
        *(float4*)(out + (size_t)b * C_ * N_ + (size_t)(o0 + o) * N_ + n0 + f4 * 4) =
            *(const float4*)(&ot2[o][f4 * 4]);
    }
}

// ---------------------------------------------------------------------------
extern "C" void kernel_launch(void* const* d_in, const int* in_sizes, int n_in,
                              void* d_out, int out_size, void* d_ws, size_t ws_size,
                              hipStream_t stream) {
    const float* x   = (const float*)d_in[0];
    const float* Wq  = (const float*)d_in[1];
    const float* Wk  = (const float*)d_in[2];
    const float* Wv  = (const float*)d_in[3];
    const float* Wo  = (const float*)d_in[4];
    const float* bo  = (const float*)d_in[5];
    const float* Wa1 = (const float*)d_in[6];
    const float* ba1 = (const float*)d_in[7];
    const float* Wa2 = (const float*)d_in[8];
    const float* ba2 = (const float*)d_in[9];
    float* out = (float*)d_out;

    const size_t PXC = (size_t)B_ * N_ * C_;   // 802816
    float* q    = (float*)d_ws;
    float* k    = q + PXC;
    float* v    = k + PXC;
    float* ao   = v + PXC;
    float* aval = ao + PXC;                    // B*H*MW = 3136 floats

    qkv_kernel  <<<dim3(N_ / 64, 6, B_), 256, 0, stream>>>(x, Wq, Wk, Wv, q, k, v);
    asym_kernel <<<dim3(MW_ / 4, H_, B_), 128, 0, stream>>>(x, Wa1, ba1, Wa2, ba2, aval);
    attn_kernel <<<(B_ * HEADS_ * N_ * 4) / 256, 256, 0, stream>>>(q, k, v, aval, ao);
    oproj_kernel<<<dim3(N_ / 64, 2, B_), 256, 0, stream>>>(ao, Wo, bo, out);
}

// Round 3
// 96.920 us; speedup vs baseline: 2.9484x; 1.2892x over previous
//
#include <hip/hip_runtime.h>
#include <hip/hip_bf16.h>
#include <math.h>

#define B_ 2
#define C_ 128
#define H_ 56
#define W_ 56
#define N_ (H_*W_)      // 3136
#define HEADS_ 4
#define DH_ 32
#define MW_ 28          // W/2
#define NPOS_ (H_*MW_)  // 1568

typedef __bf16 v8bf __attribute__((ext_vector_type(8)));
typedef float  v4f  __attribute__((ext_vector_type(4)));

#define MFMA16(a,b,c) __builtin_amdgcn_mfma_f32_16x16x32_bf16((a),(b),(c),0,0,0)

__device__ __forceinline__ unsigned short f2bf(float f) {
    return __builtin_bit_cast(unsigned short, __float2bfloat16(f));
}

// ---------------------------------------------------------------------------
// Kernel 1: fused qkv projections (blockIdx.y 0..5, MFMA 64px x 64out tiles)
//           + asym gate (blockIdx.y == 6, MFMA 128hidden x 32pos, K=256).
// LDS rows padded to 136 bf16 (68 dw, delta-row = 4 mod 32 -> 2-way = free).
// ---------------------------------------------------------------------------
__global__ __launch_bounds__(256)
void qkv_asym_kernel(const float* __restrict__ x,
                     const float* __restrict__ Wq, const float* __restrict__ Wk,
                     const float* __restrict__ Wv,
                     const float* __restrict__ Wa1, const float* __restrict__ ba1,
                     const float* __restrict__ Wa2, const float* __restrict__ ba2,
                     float* __restrict__ q, float* __restrict__ k,
                     float* __restrict__ v, float* __restrict__ aval) {
    __shared__ __align__(16) char smem[35840];
    const int t = threadIdx.x;
    const int b = blockIdx.z;
    const int wv_ = t >> 6;      // wave 0..3
    const int l   = t & 63;
    const int lr  = l & 15;      // frag row/col-in-tile
    const int lq  = l >> 4;      // frag quad

    if (blockIdx.y < 6) {
        // ---------------- q/k/v projection path ----------------
        unsigned short* WT = (unsigned short*)smem;            // [64][136]
        unsigned short* XT = (unsigned short*)(smem + 17408);  // [64][136]
        float* ep = (float*)smem;                              // [64][68]

        const int n0  = blockIdx.x * 64;
        const int mIdx = blockIdx.y >> 1;
        const int o0  = (blockIdx.y & 1) * 64;
        const float* W = (mIdx == 0 ? Wq : (mIdx == 1 ? Wk : Wv));
        float* dst     = (mIdx == 0 ? q  : (mIdx == 1 ? k  : v ));
        const float* xb = x + (size_t)b * C_ * N_;

        // stage W tile: 64 rows x 32 float4, coalesced; bf16 into LDS
        for (int it = 0; it < 8; ++it) {
            int idx = t + it * 256;
            int row = idx >> 5, f4 = idx & 31;
            float4 w4 = *(const float4*)(W + (size_t)(o0 + row) * C_ + f4 * 4);
            ushort4 p4 = { f2bf(w4.x), f2bf(w4.y), f2bf(w4.z), f2bf(w4.w) };
            *(ushort4*)(WT + row * 136 + f4 * 4) = p4;
        }
        // stage X^T tile: lane = pixel (coalesced 256B rows), gather 4 ch/iter
        {
            int px = t & 63, g = t >> 6;
            const float* xc = xb + n0 + px;
            for (int it = 0; it < 8; ++it) {
                int c0 = (g + it * 4) * 4;          // channel quad base
                float a0 = xc[(size_t)(c0 + 0) * N_];
                float a1 = xc[(size_t)(c0 + 1) * N_];
                float a2 = xc[(size_t)(c0 + 2) * N_];
                float a3 = xc[(size_t)(c0 + 3) * N_];
                ushort4 p4 = { f2bf(a0), f2bf(a1), f2bf(a2), f2bf(a3) };
                *(ushort4*)(XT + px * 136 + c0) = p4;
            }
        }
        __syncthreads();

        v4f acc[4];
        #pragma unroll
        for (int nt = 0; nt < 4; ++nt) acc[nt] = (v4f){0.f, 0.f, 0.f, 0.f};

        #pragma unroll
        for (int ks = 0; ks < 4; ++ks) {
            v8bf af = *(const v8bf*)(WT + (wv_ * 16 + lr) * 136 + ks * 32 + lq * 8);
            #pragma unroll
            for (int nt = 0; nt < 4; ++nt) {
                v8bf bfr = *(const v8bf*)(XT + (nt * 16 + lr) * 136 + ks * 32 + lq * 8);
                acc[nt] = MFMA16(af, bfr, acc[nt]);
            }
        }

        // epilogue: transpose via LDS -> coalesced float4 stores, pixel-major
        __syncthreads();
        #pragma unroll
        for (int nt = 0; nt < 4; ++nt)
            #pragma unroll
            for (int r = 0; r < 4; ++r)
                ep[(nt * 16 + lr) * 68 + wv_ * 16 + lq * 4 + r] = acc[nt][r];
        __syncthreads();
        for (int it = 0; it < 4; ++it) {
            int idx = t + it * 256;
            int p = idx >> 4, f4 = idx & 15;
            *(float4*)(dst + ((size_t)b * N_ + n0 + p) * C_ + o0 + f4 * 4) =
                *(const float4*)(ep + p * 68 + f4 * 4);
        }
    } else {
        // ---------------- asym gate path ----------------
        unsigned short* wa  = (unsigned short*)smem;            // [128][72]
        unsigned short* cat = (unsigned short*)(smem + 18432);  // [32][264]
        float* wred = (float*)(smem + 35328);                   // [4][32]

        const int P0 = blockIdx.x * 32;                         // 49*32 = 1568
        const float* xb = x + (size_t)b * C_ * N_;

        // stage cat = [left(128) ; flip(right)(128)] as bf16 [pos][ch]
        {
            int pos = t & 31, chg = t >> 5;                     // chg 0..7
            int pg = P0 + pos;
            int h = pg / MW_, j = pg - h * MW_;
            int col = (chg < 4) ? (h * W_ + j) : (h * W_ + (W_ - 1 - j));
            int cbase = (chg & 3) * 32;
            const float* src = xb + col;
            unsigned short* crow = cat + pos * 264 + chg * 32;
            #pragma unroll
            for (int u = 0; u < 16; ++u) {
                float f0 = src[(size_t)(cbase + 2 * u) * N_];
                float f1 = src[(size_t)(cbase + 2 * u + 1) * N_];
                ushort2 pp = { f2bf(f0), f2bf(f1) };
                *(ushort2*)(crow + 2 * u) = pp;
            }
        }

        v4f acc2[2][2];
        #pragma unroll
        for (int mi = 0; mi < 2; ++mi)
            #pragma unroll
            for (int nt = 0; nt < 2; ++nt) acc2[mi][nt] = (v4f){0.f, 0.f, 0.f, 0.f};

        for (int kc = 0; kc < 4; ++kc) {
            __syncthreads();     // also covers initial cat staging (kc==0)
            for (int it = 0; it < 8; ++it) {
                int idx = t + it * 256;
                int row = idx >> 4, f4 = idx & 15;
                float4 w4 = *(const float4*)(Wa1 + (size_t)row * 256 + kc * 64 + f4 * 4);
                ushort4 p4 = { f2bf(w4.x), f2bf(w4.y), f2bf(w4.z), f2bf(w4.w) };
                *(ushort4*)(wa + row * 72 + f4 * 4) = p4;
            }
            __syncthreads();
            #pragma unroll
            for (int ks = 0; ks < 2; ++ks) {
                v8bf a0f = *(const v8bf*)(wa + ((2*wv_ + 0) * 16 + lr) * 72 + ks * 32 + lq * 8);
                v8bf a1f = *(const v8bf*)(wa + ((2*wv_ + 1) * 16 + lr) * 72 + ks * 32 + lq * 8);
                v8bf b0f = *(const v8bf*)(cat + lr * 264        + kc * 64 + ks * 32 + lq * 8);
                v8bf b1f = *(const v8bf*)(cat + (16 + lr) * 264 + kc * 64 + ks * 32 + lq * 8);
                acc2[0][0] = MFMA16(a0f, b0f, acc2[0][0]);
                acc2[0][1] = MFMA16(a0f, b1f, acc2[0][1]);
                acc2[1][0] = MFMA16(a1f, b0f, acc2[1][0]);
                acc2[1][1] = MFMA16(a1f, b1f, acc2[1][1]);
            }
        }

        // gelu(hidden + ba1) * Wa2, reduce over hidden(128) per pos
        float p2[2] = {0.f, 0.f};
        #pragma unroll
        for (int mi = 0; mi < 2; ++mi) {
            #pragma unroll
            for (int r = 0; r < 4; ++r) {
                int m = (2*wv_ + mi) * 16 + lq * 4 + r;
                float wa2v = Wa2[m];
                float b1v  = ba1[m];
                #pragma unroll
                for (int nt = 0; nt < 2; ++nt) {
                    float val = acc2[mi][nt][r] + b1v;
                    float gl = 0.5f * val * (1.0f + erff(val * 0.7071067811865475f));
                    p2[nt] += gl * wa2v;
                }
            }
        }
        #pragma unroll
        for (int nt = 0; nt < 2; ++nt) {
            p2[nt] += __shfl_xor(p2[nt], 16, 64);
            p2[nt] += __shfl_xor(p2[nt], 32, 64);
        }
        if (l < 16) {
            wred[wv_ * 32 + lr]      = p2[0];
            wred[wv_ * 32 + 16 + lr] = p2[1];
        }
        __syncthreads();
        if (t < 32) {
            float s = wred[t] + wred[32 + t] + wred[64 + t] + wred[96 + t] + ba2[0];
            aval[(size_t)b * NPOS_ + P0 + t] = 1.0f / (1.0f + expf(-s));
        }
    }
}

// ---------------------------------------------------------------------------
// Kernel 2: 3x3 neighborhood attention + asym gating (fp32).
// 4 lanes per (b,head,n); writes ao PIXEL-major [b][n][c], scaled.
// ---------------------------------------------------------------------------
__global__ __launch_bounds__(256)
void attn_kernel(const float* __restrict__ q, const float* __restrict__ k,
                 const float* __restrict__ v, const float* __restrict__ aval,
                 float* __restrict__ ao) {
    const int gid = blockIdx.x * 256 + threadIdx.x;   // B*HEADS*N*4 = 100352
    const int s    = gid & 3;
    const int rest = gid >> 2;
    const int n    = rest % N_;
    const int hb   = rest / N_;
    const int head = hb & (HEADS_ - 1);
    const int b    = hb >> 2;
    const int i = n / W_, j = n - i * W_;
    const int dbase = head * DH_ + s * 8;

    const float* qp = q + ((size_t)b * N_ + n) * C_ + dbase;
    const float4 q0 = *(const float4*)qp;
    const float4 q1 = *(const float4*)(qp + 4);

    float dts[9];
    int   mm[9];
    #pragma unroll
    for (int tt = 0; tt < 9; ++tt) {
        int di = tt / 3 - 1, dj = tt % 3 - 1;
        int ii = i + di, jj = j + dj;
        bool ok = ((unsigned)ii < (unsigned)H_) && ((unsigned)jj < (unsigned)W_);
        int m = ok ? ii * W_ + jj : n;
        mm[tt] = m;
        const float* kp = k + ((size_t)b * N_ + m) * C_ + dbase;
        float4 k0 = *(const float4*)kp;
        float4 k1 = *(const float4*)(kp + 4);
        float pd = q0.x*k0.x + q0.y*k0.y + q0.z*k0.z + q0.w*k0.w
                 + q1.x*k1.x + q1.y*k1.y + q1.z*k1.z + q1.w*k1.w;
        pd += __shfl_xor(pd, 1, 64);
        pd += __shfl_xor(pd, 2, 64);
        dts[tt] = ok ? pd * 0.17677669529663687f : -1e30f;
    }
    float mx = dts[0];
    #pragma unroll
    for (int tt = 1; tt < 9; ++tt) mx = fmaxf(mx, dts[tt]);
    float sum = 0.f;
    #pragma unroll
    for (int tt = 0; tt < 9; ++tt) { dts[tt] = expf(dts[tt] - mx); sum += dts[tt]; }
    const float inv = 1.0f / sum;

    float4 a0 = {0,0,0,0}, a1 = {0,0,0,0};
    #pragma unroll
    for (int tt = 0; tt < 9; ++tt) {
        const float* vp = v + ((size_t)b * N_ + mm[tt]) * C_ + dbase;
        float4 v0 = *(const float4*)vp;
        float4 v1 = *(const float4*)(vp + 4);
        float wt = dts[tt] * inv;
        a0.x += wt * v0.x; a0.y += wt * v0.y; a0.z += wt * v0.z; a0.w += wt * v0.w;
        a1.x += wt * v1.x; a1.y += wt * v1.y; a1.z += wt * v1.z; a1.w += wt * v1.w;
    }

    float f = 0.5f * (float)j - 0.25f;
    f = fminf(fmaxf(f, 0.0f), 27.0f);
    int i0 = (int)f; if (i0 > 26) i0 = 26;
    float frac = f - (float)i0;
    const float* av = aval + (size_t)b * NPOS_ + i * MW_;
    float a = av[i0] * (1.0f - frac) + av[i0 + 1] * frac;
    float sc = 1.0f + 0.5f * a;

    float* op = ao + ((size_t)b * N_ + n) * C_ + dbase;
    float4 r0 = { a0.x*sc, a0.y*sc, a0.z*sc, a0.w*sc };
    float4 r1 = { a1.x*sc, a1.y*sc, a1.z*sc, a1.w*sc };
    *(float4*)op       = r0;
    *(float4*)(op + 4) = r1;
}

// ---------------------------------------------------------------------------
// Kernel 3: output projection, MFMA 64px x 64out; ao pixel-major in (no
// transpose staging), out channel-major (d_out layout), bias added.
// ---------------------------------------------------------------------------
__global__ __launch_bounds__(256)
void oproj_kernel(const float* __restrict__ ao, const float* __restrict__ Wo,
                  const float* __restrict__ bo, float* __restrict__ out) {
    __shared__ __align__(16) char smem[34816];
    unsigned short* WT = (unsigned short*)smem;            // [64][136]
    unsigned short* XT = (unsigned short*)(smem + 17408);  // [64][136]
    float* ep = (float*)smem;                              // [64][68]

    const int t = threadIdx.x;
    const int n0 = blockIdx.x * 64;
    const int o0 = blockIdx.y * 64;
    const int b  = blockIdx.z;
    const int wv_ = t >> 6, l = t & 63, lr = l & 15, lq = l >> 4;

    for (int it = 0; it < 8; ++it) {
        int idx = t + it * 256;
        int row = idx >> 5, f4 = idx & 31;
        float4 w4 = *(const float4*)(Wo + (size_t)(o0 + row) * C_ + f4 * 4);
        ushort4 p4 = { f2bf(w4.x), f2bf(w4.y), f2bf(w4.z), f2bf(w4.w) };
        *(ushort4*)(WT + row * 136 + f4 * 4) = p4;
    }
    for (int it = 0; it < 8; ++it) {
        int idx = t + it * 256;
        int row = idx >> 5, f4 = idx & 31;   // row = px, contiguous channels
        float4 a4 = *(const float4*)(ao + ((size_t)b * N_ + n0 + row) * C_ + f4 * 4);
        ushort4 p4 = { f2bf(a4.x), f2bf(a4.y), f2bf(a4.z), f2bf(a4.w) };
        *(ushort4*)(XT + row * 136 + f4 * 4) = p4;
    }
    __syncthreads();

    v4f acc[4];
    #pragma unroll
    for (int nt = 0; nt < 4; ++nt) acc[nt] = (v4f){0.f, 0.f, 0.f, 0.f};

    #pragma unroll
    for (int ks = 0; ks < 4; ++ks) {
        v8bf af = *(const v8bf*)(WT + (wv_ * 16 + lr) * 136 + ks * 32 + lq * 8);
        #pragma unroll
        for (int nt = 0; nt < 4; ++nt) {
            v8bf bfr = *(const v8bf*)(XT + (nt * 16 + lr) * 136 + ks * 32 + lq * 8);
            acc[nt] = MFMA16(af, bfr, acc[nt]);
        }
    }

    __syncthreads();
    const float4 bv = *(const float4*)(bo + o0 + wv_ * 16 + lq * 4);
    const float bvr[4] = { bv.x, bv.y, bv.z, bv.w };
    #pragma unroll
    for (int nt = 0; nt < 4; ++nt)
        #pragma unroll
        for (int r = 0; r < 4; ++r)
            ep[(wv_ * 16 + lq * 4 + r) * 68 + nt * 16 + lr] = acc[nt][r] + bvr[r];
    __syncthreads();
    for (int it = 0; it < 4; ++it) {
        int idx = t + it * 256;
        int o = idx >> 4, f4 = idx & 15;
        *(float4*)(out + (size_t)b * C_ * N_ + (size_t)(o0 + o) * N_ + n0 + f4 * 4) =
            *(const float4*)(ep + o * 68 + f4 * 4);
    }
}

// ---------------------------------------------------------------------------
extern "C" void kernel_launch(void* const* d_in, const int* in_sizes, int n_in,
                              void* d_out, int out_size, void* d_ws, size_t ws_size,
                              hipStream_t stream) {
    const float* x   = (const float*)d_in[0];
    const float* Wq  = (const float*)d_in[1];
    const float* Wk  = (const float*)d_in[2];
    const float* Wv  = (const float*)d_in[3];
    const float* Wo  = (const float*)d_in[4];
    const float* bo  = (const float*)d_in[5];
    const float* Wa1 = (const float*)d_in[6];
    const float* ba1 = (const float*)d_in[7];
    const float* Wa2 = (const float*)d_in[8];
    const float* ba2 = (const float*)d_in[9];
    float* out = (float*)d_out;

    const size_t PXC = (size_t)B_ * N_ * C_;   // 802816
    float* q    = (float*)d_ws;
    float* k    = q + PXC;
    float* v    = k + PXC;
    float* ao   = v + PXC;
    float* aval = ao + PXC;                    // B*NPOS_ floats

    qkv_asym_kernel<<<dim3(49, 7, B_), 256, 0, stream>>>(
        x, Wq, Wk, Wv, Wa1, ba1, Wa2, ba2, q, k, v, aval);
    attn_kernel<<<(B_ * HEADS_ * N_ * 4) / 256, 256, 0, stream>>>(q, k, v, aval, ao);
    oproj_kernel<<<dim3(49, 2, B_), 256, 0, stream>>>(ao, Wo, bo, out);
}